// Round 1
// baseline (273.496 us; speedup 1.0000x reference)
//
#include <hip/hip_runtime.h>
#include <hip/hip_bf16.h>
#include <stdint.h>

typedef unsigned short u16;
typedef __attribute__((ext_vector_type(4))) float f32x4;
typedef __attribute__((ext_vector_type(8))) short bf16x8;

#define B_ 2
#define S_ 2048
#define H_ 16
#define D_ 1024
#define XELEMS (B_*S_*D_)      // 4194304 per tensor
#define WELEMS (D_*D_)         // 1048576 per weight

__device__ __forceinline__ u16 f2bf(float f) {
  union { float f; unsigned u; } v; v.f = f;
  unsigned r = v.u + 0x7fffu + ((v.u >> 16) & 1u);
  return (u16)(r >> 16);
}

__device__ __forceinline__ void async16(const void* g, void* l) {
  __builtin_amdgcn_global_load_lds(
      (const __attribute__((address_space(1))) unsigned int*)g,
      (__attribute__((address_space(3))) unsigned int*)l, 16, 0, 0);
}

// ---------------- prep: f32 -> bf16 convert (vectorized) ----------------
__global__ __launch_bounds__(256) void convert_x(
    const float* __restrict__ q, const float* __restrict__ k,
    const float* __restrict__ v, u16* __restrict__ out) {
  const int ngrp = XELEMS / 8;           // groups of 8 per tensor
  const int total = 3 * ngrp;
  for (int i = blockIdx.x * blockDim.x + threadIdx.x; i < total;
       i += gridDim.x * blockDim.x) {
    int which = i / ngrp;
    int off = (i - which * ngrp) * 8;
    const float* src = (which == 0) ? q : (which == 1) ? k : v;
    float4 a = *(const float4*)(src + off);
    float4 b = *(const float4*)(src + off + 4);
    u16 r[8] = {f2bf(a.x), f2bf(a.y), f2bf(a.z), f2bf(a.w),
                f2bf(b.x), f2bf(b.y), f2bf(b.z), f2bf(b.w)};
    uint4 pk;
    pk.x = (unsigned)r[0] | ((unsigned)r[1] << 16);
    pk.y = (unsigned)r[2] | ((unsigned)r[3] << 16);
    pk.z = (unsigned)r[4] | ((unsigned)r[5] << 16);
    pk.w = (unsigned)r[6] | ((unsigned)r[7] << 16);
    *(uint4*)(out + which * XELEMS + off) = pk;
  }
}

// ---------------- prep: W (f32, [K][N]) -> W^T (bf16, [N][K]) ----------------
__global__ __launch_bounds__(256) void transpose_w(
    const float* __restrict__ Wq, const float* __restrict__ Wk,
    const float* __restrict__ Wv, const float* __restrict__ Wo,
    u16* __restrict__ out) {
  __shared__ float tile[32][33];
  const int z = blockIdx.z;
  const float* W = (z == 0) ? Wq : (z == 1) ? Wk : (z == 2) ? Wv : Wo;
  u16* o = out + z * WELEMS;
  const int r0 = blockIdx.y * 32, c0 = blockIdx.x * 32;
  const int tx = threadIdx.x & 31, ty = threadIdx.x >> 5;
  #pragma unroll
  for (int rr = ty; rr < 32; rr += 8)
    tile[rr][tx] = W[(r0 + rr) * D_ + c0 + tx];
  __syncthreads();
  #pragma unroll
  for (int rr = ty; rr < 32; rr += 8)
    o[(c0 + rr) * D_ + r0 + tx] = f2bf(tile[tx][rr]);
}

// ---------------- GEMM: C[M,1024] = A[M,1024] @ BT^T + bias ----------------
// MODE 0: out bf16, head-split scatter [B,H,S,64].  MODE 1: out f32 row-major.
template <int MODE>
__device__ __forceinline__ void gemm_body(const u16* __restrict__ A,
                                          const u16* __restrict__ BT,
                                          const float* __restrict__ bias,
                                          void* __restrict__ outp,
                                          int bm, int bn) {
  __shared__ __align__(16) u16 As[128 * 32];
  __shared__ __align__(16) u16 Bs[128 * 32];
  const int tid = threadIdx.x;
  const int w = tid >> 6, l = tid & 63;
  const int wr = w >> 1, wc = w & 1;
  const int g = l >> 4, r = l & 15;

  f32x4 acc[4][4];
  #pragma unroll
  for (int i = 0; i < 4; i++)
    #pragma unroll
    for (int j = 0; j < 4; j++) acc[i][j] = (f32x4){0.f, 0.f, 0.f, 0.f};

  const int srow = l >> 2;
  const int scol = (l & 3) * 8;
  const u16* Ab = A + (bm + w * 16 + srow) * 1024 + scol;
  const u16* Bb = BT + (bn + w * 16 + srow) * 1024 + scol;
  u16* AsW = &As[(w * 16 + srow) * 32 + scol];
  u16* BsW = &Bs[(w * 16 + srow) * 32 + scol];

  for (int k0 = 0; k0 < 1024; k0 += 32) {
    async16(Ab + k0, AsW);
    async16(Ab + 64 * 1024 + k0, AsW + 64 * 32);
    async16(Bb + k0, BsW);
    async16(Bb + 64 * 1024 + k0, BsW + 64 * 32);
    __syncthreads();
    bf16x8 af[4], bf[4];
    #pragma unroll
    for (int mi = 0; mi < 4; mi++)
      af[mi] = *(const bf16x8*)&As[(wr * 64 + mi * 16 + r) * 32 + g * 8];
    #pragma unroll
    for (int ni = 0; ni < 4; ni++)
      bf[ni] = *(const bf16x8*)&Bs[(wc * 64 + ni * 16 + r) * 32 + g * 8];
    #pragma unroll
    for (int mi = 0; mi < 4; mi++)
      #pragma unroll
      for (int ni = 0; ni < 4; ni++)
        acc[mi][ni] = __builtin_amdgcn_mfma_f32_16x16x32_bf16(
            af[mi], bf[ni], acc[mi][ni], 0, 0, 0);
    __syncthreads();
  }

  const int col0 = bn + wc * 64;
  float bc[4];
  #pragma unroll
  for (int ni = 0; ni < 4; ni++) bc[ni] = bias[col0 + ni * 16 + r];

  if (MODE == 0) {
    u16* out = (u16*)outp;
    #pragma unroll
    for (int mi = 0; mi < 4; mi++) {
      const int row = bm + wr * 64 + mi * 16 + g * 4;
      #pragma unroll
      for (int ni = 0; ni < 4; ni++) {
        const int col = col0 + ni * 16 + r;
        const int h = col >> 6, dk = col & 63;
        #pragma unroll
        for (int i = 0; i < 4; i++) {
          const int rr = row + i;
          const int b = rr >> 11, s = rr & 2047;
          out[(((b << 4) | h) * 2048 + s) * 64 + dk] =
              f2bf(acc[mi][ni][i] + bc[ni]);
        }
      }
    }
  } else {
    float* out = (float*)outp;
    #pragma unroll
    for (int mi = 0; mi < 4; mi++) {
      const int row = bm + wr * 64 + mi * 16 + g * 4;
      #pragma unroll
      for (int ni = 0; ni < 4; ni++) {
        const int col = col0 + ni * 16 + r;
        #pragma unroll
        for (int i = 0; i < 4; i++)
          out[(row + i) * 1024 + col] = acc[mi][ni][i] + bc[ni];
      }
    }
  }
}

__global__ __launch_bounds__(256) void gemm_qkv_k(
    const u16* __restrict__ X, const u16* __restrict__ WT,
    const float* __restrict__ bq, const float* __restrict__ bk,
    const float* __restrict__ bv, u16* __restrict__ QKV) {
  const int z = blockIdx.z;
  const float* bias = (z == 0) ? bq : (z == 1) ? bk : bv;
  gemm_body<0>(X + z * XELEMS, WT + z * WELEMS, bias, QKV + z * XELEMS,
               blockIdx.x * 128, blockIdx.y * 128);
}

__global__ __launch_bounds__(256) void gemm_o_k(
    const u16* __restrict__ O, const u16* __restrict__ WOT,
    const float* __restrict__ bo, float* __restrict__ out) {
  gemm_body<1>(O, WOT, bo, out, blockIdx.x * 128, blockIdx.y * 128);
}

// ---------------- causal flash attention ----------------
// Q/K/V: [B*H][S][64] bf16. O: [B][S][H*64] bf16 (merged heads).
// Block: 4 waves, 128 q rows (32/wave). KV tiles of 32.
__global__ __launch_bounds__(256) void attn_k(
    const u16* __restrict__ Qh, const u16* __restrict__ Kh,
    const u16* __restrict__ Vh, u16* __restrict__ O) {
  __shared__ __align__(16) u16 ldsK[32 * 64];   // swizzled rows
  __shared__ __align__(16) u16 ldsV[64 * 32];   // transposed + swizzled
  __shared__ __align__(16) u16 ldsP[4 * 32 * 40];

  const int bh = blockIdx.y;       // b*16 + h
  const int qblk = blockIdx.x;     // 0..15
  const int tid = threadIdx.x;
  const int w = tid >> 6, l = tid & 63;
  const int g = l >> 4, r = l & 15;
  const int q0w = qblk * 128 + w * 32;
  const int b = bh >> 4, h = bh & 15;

  const u16* Qp = Qh + bh * (S_ * 64);
  const u16* Kp = Kh + bh * (S_ * 64);
  const u16* Vp = Vh + bh * (S_ * 64);

  // Q fragments held in registers for the whole KV loop
  bf16x8 qf[2][2];
  #pragma unroll
  for (int m = 0; m < 2; m++)
    #pragma unroll
    for (int dh = 0; dh < 2; dh++)
      qf[m][dh] = *(const bf16x8*)(Qp + (q0w + m * 16 + r) * 64 + dh * 32 + g * 8);

  f32x4 acc[2][4];
  #pragma unroll
  for (int m = 0; m < 2; m++)
    #pragma unroll
    for (int n = 0; n < 4; n++) acc[m][n] = (f32x4){0.f, 0.f, 0.f, 0.f};
  float mrow[2][4], lrow[2][4];
  #pragma unroll
  for (int m = 0; m < 2; m++)
    #pragma unroll
    for (int i = 0; i < 4; i++) { mrow[m][i] = -1e30f; lrow[m][i] = 0.f; }

  u16* Pw = &ldsP[w * 1280];
  const int nt = qblk * 4 + 4;

  for (int t = 0; t < nt; ++t) {
    const int kv0 = t * 32;
    // --- stage K (async, source pre-swizzled so linear LDS write = swizzled image)
    {
      const int o = w * 1024 + l * 16;                // byte offset in 4KB tile
      const int src = o ^ (((o >> 7) & 7) << 4);
      async16((const char*)Kp + kv0 * 128 + src, (char*)ldsK + o);
    }
    // --- stage V transposed (reg path), swizzled
    {
      uint4 vv = *(const uint4*)((const char*)Vp + kv0 * 128 + tid * 16);
      const u16* vs = (const u16*)&vv;
      const int kk = tid >> 3, d0 = (tid & 7) * 8;
      #pragma unroll
      for (int j = 0; j < 8; j++) {
        const int d = d0 + j;
        int idx = d * 32 + kk;
        idx ^= ((d >> 1) & 3) << 3;
        ldsV[idx] = vs[j];
      }
    }
    __syncthreads();

    if (kv0 <= q0w + 31) {
      // K fragments (swizzled read)
      bf16x8 kf[2][2];
      #pragma unroll
      for (int ct = 0; ct < 2; ct++)
        #pragma unroll
        for (int dh = 0; dh < 2; dh++) {
          const int row = ct * 16 + r;
          const int byt = (row * 128 + dh * 64 + g * 16) ^ ((row & 7) << 4);
          kf[ct][dh] = *(const bf16x8*)((const char*)ldsK + byt);
        }
      // scores
      f32x4 sc[2][2];
      #pragma unroll
      for (int m = 0; m < 2; m++)
        #pragma unroll
        for (int ct = 0; ct < 2; ct++) {
          f32x4 z4 = (f32x4){0.f, 0.f, 0.f, 0.f};
          z4 = __builtin_amdgcn_mfma_f32_16x16x32_bf16(qf[m][0], kf[ct][0], z4, 0, 0, 0);
          sc[m][ct] = __builtin_amdgcn_mfma_f32_16x16x32_bf16(qf[m][1], kf[ct][1], z4, 0, 0, 0);
        }
      // scale + causal mask
      const bool need_mask = (kv0 + 31 > q0w);
      #pragma unroll
      for (int m = 0; m < 2; m++)
        #pragma unroll
        for (int ct = 0; ct < 2; ct++)
          #pragma unroll
          for (int i = 0; i < 4; i++) {
            float vsc = sc[m][ct][i] * 0.125f;
            if (need_mask) {
              const int rq = q0w + m * 16 + g * 4 + i;
              const int ck = kv0 + ct * 16 + r;
              vsc = (ck > rq) ? -1e30f : vsc;
            }
            sc[m][ct][i] = vsc;
          }
      // online softmax (per 16-row subtile)
      #pragma unroll
      for (int m = 0; m < 2; m++) {
        float pmax[4];
        #pragma unroll
        for (int i = 0; i < 4; i++) pmax[i] = fmaxf(sc[m][0][i], sc[m][1][i]);
        for (int dm = 1; dm < 16; dm <<= 1) {
          #pragma unroll
          for (int i = 0; i < 4; i++)
            pmax[i] = fmaxf(pmax[i], __shfl_xor(pmax[i], dm, 64));
        }
        float mnew[4], corr[4];
        #pragma unroll
        for (int i = 0; i < 4; i++) {
          mnew[i] = fmaxf(mrow[m][i], pmax[i]);
          corr[i] = __expf(mrow[m][i] - mnew[i]);
          mrow[m][i] = mnew[i];
        }
        #pragma unroll
        for (int n = 0; n < 4; n++)
          #pragma unroll
          for (int i = 0; i < 4; i++) acc[m][n][i] *= corr[i];
        float psum[4] = {0.f, 0.f, 0.f, 0.f};
        #pragma unroll
        for (int ct = 0; ct < 2; ct++)
          #pragma unroll
          for (int i = 0; i < 4; i++) {
            const float p = __expf(sc[m][ct][i] - mnew[i]);
            sc[m][ct][i] = p;
            psum[i] += p;
          }
        for (int dm = 1; dm < 16; dm <<= 1) {
          #pragma unroll
          for (int i = 0; i < 4; i++) psum[i] += __shfl_xor(psum[i], dm, 64);
        }
        #pragma unroll
        for (int i = 0; i < 4; i++) lrow[m][i] = lrow[m][i] * corr[i] + psum[i];
        // P -> LDS (bf16), C-layout to A-layout transpose
        #pragma unroll
        for (int ct = 0; ct < 2; ct++)
          #pragma unroll
          for (int i = 0; i < 4; i++)
            Pw[(m * 16 + g * 4 + i) * 40 + ct * 16 + r] = f2bf(sc[m][ct][i]);
      }
      asm volatile("s_waitcnt lgkmcnt(0)" ::: "memory");
      bf16x8 pf[2];
      #pragma unroll
      for (int m = 0; m < 2; m++)
        pf[m] = *(const bf16x8*)&Pw[(m * 16 + r) * 40 + g * 8];
      bf16x8 vf[4];
      #pragma unroll
      for (int n = 0; n < 4; n++) {
        const int dcol = n * 16 + r;
        const int idx = (dcol * 32 + g * 8) ^ (((dcol >> 1) & 3) << 3);
        vf[n] = *(const bf16x8*)&ldsV[idx];
      }
      #pragma unroll
      for (int m = 0; m < 2; m++)
        #pragma unroll
        for (int n = 0; n < 4; n++)
          acc[m][n] = __builtin_amdgcn_mfma_f32_16x16x32_bf16(pf[m], vf[n], acc[m][n], 0, 0, 0);
    }
    __syncthreads();
  }

  // epilogue: O[b][s][h*64+d] = acc / l
  #pragma unroll
  for (int m = 0; m < 2; m++)
    #pragma unroll
    for (int n = 0; n < 4; n++)
      #pragma unroll
      for (int i = 0; i < 4; i++) {
        const int s = q0w + m * 16 + g * 4 + i;
        const int d = n * 16 + r;
        O[(b * 2048 + s) * 1024 + h * 64 + d] = f2bf(acc[m][n][i] / lrow[m][i]);
      }
}

// ---------------- launcher ----------------
extern "C" void kernel_launch(void* const* d_in, const int* in_sizes, int n_in,
                              void* d_out, int out_size, void* d_ws, size_t ws_size,
                              hipStream_t stream) {
  const float* q  = (const float*)d_in[0];
  const float* k  = (const float*)d_in[1];
  const float* v  = (const float*)d_in[2];
  // d_in[3] = mask (causal triu) — applied analytically
  const float* Wq = (const float*)d_in[4];
  const float* bq = (const float*)d_in[5];
  const float* Wk = (const float*)d_in[6];
  const float* bk = (const float*)d_in[7];
  const float* Wv = (const float*)d_in[8];
  const float* bv = (const float*)d_in[9];
  const float* Wo = (const float*)d_in[10];
  const float* bo = (const float*)d_in[11];

  char* ws = (char*)d_ws;
  const size_t MB = 1u << 20;
  u16* X   = (u16*)(ws);             // 3 x XELEMS bf16 (24MB)
  u16* WT  = (u16*)(ws + 24 * MB);   // 4 x WELEMS bf16 (8MB)
  u16* QKV = (u16*)(ws + 32 * MB);   // 3 x XELEMS bf16 (24MB)
  u16* O   = (u16*)(ws);             // reuse X region after projections

  hipLaunchKernelGGL(convert_x, dim3(1024), dim3(256), 0, stream, q, k, v, X);
  hipLaunchKernelGGL(transpose_w, dim3(32, 32, 4), dim3(256), 0, stream,
                     Wq, Wk, Wv, Wo, WT);
  hipLaunchKernelGGL(gemm_qkv_k, dim3(32, 8, 3), dim3(256), 0, stream,
                     X, WT, bq, bk, bv, QKV);
  hipLaunchKernelGGL(attn_k, dim3(16, 32), dim3(256), 0, stream,
                     QKV, QKV + XELEMS, QKV + 2 * XELEMS, O);
  hipLaunchKernelGGL(gemm_o_k, dim3(32, 8), dim3(256), 0, stream,
                     O, WT + 3 * WELEMS, bo, (float*)d_out);
}

// Round 3
// 147.666 us; speedup vs baseline: 1.8521x; 1.8521x over previous
//
#include <hip/hip_runtime.h>
#include <hip/hip_bf16.h>
#include <stdint.h>

typedef unsigned short u16;
typedef __attribute__((ext_vector_type(4))) float f32x4;
typedef __attribute__((ext_vector_type(8))) short bf16x8;
typedef __attribute__((ext_vector_type(4))) short s16x4;

#define B_ 2
#define S_ 2048
#define H_ 16
#define D_ 1024
#define XELEMS (B_*S_*D_)      // 4194304 per tensor
#define WELEMS (D_*D_)         // 1048576 per weight

__device__ __forceinline__ u16 f2bf(float f) {
  union { float f; unsigned u; } v; v.f = f;
  unsigned r = v.u + 0x7fffu + ((v.u >> 16) & 1u);
  return (u16)(r >> 16);
}

__device__ __forceinline__ void async16(const void* g, void* l) {
  __builtin_amdgcn_global_load_lds(
      (const __attribute__((address_space(1))) unsigned int*)g,
      (__attribute__((address_space(3))) unsigned int*)l, 16, 0, 0);
}

// ---------------- prep: f32 -> bf16 convert (vectorized) ----------------
__global__ __launch_bounds__(256) void convert_x(
    const float* __restrict__ q, const float* __restrict__ k,
    const float* __restrict__ v, u16* __restrict__ out) {
  const int ngrp = XELEMS / 8;
  const int total = 3 * ngrp;
  for (int i = blockIdx.x * blockDim.x + threadIdx.x; i < total;
       i += gridDim.x * blockDim.x) {
    int which = i / ngrp;
    int off = (i - which * ngrp) * 8;
    const float* src = (which == 0) ? q : (which == 1) ? k : v;
    float4 a = *(const float4*)(src + off);
    float4 b = *(const float4*)(src + off + 4);
    u16 r[8] = {f2bf(a.x), f2bf(a.y), f2bf(a.z), f2bf(a.w),
                f2bf(b.x), f2bf(b.y), f2bf(b.z), f2bf(b.w)};
    uint4 pk;
    pk.x = (unsigned)r[0] | ((unsigned)r[1] << 16);
    pk.y = (unsigned)r[2] | ((unsigned)r[3] << 16);
    pk.z = (unsigned)r[4] | ((unsigned)r[5] << 16);
    pk.w = (unsigned)r[6] | ((unsigned)r[7] << 16);
    *(uint4*)(out + which * XELEMS + off) = pk;
  }
}

// ---------------- prep: W (f32, [K][N]) -> W^T (bf16, [N][K]) ----------------
__global__ __launch_bounds__(256) void transpose_w(
    const float* __restrict__ Wq, const float* __restrict__ Wk,
    const float* __restrict__ Wv, const float* __restrict__ Wo,
    u16* __restrict__ out) {
  __shared__ float tile[32][33];
  const int z = blockIdx.z;
  const float* W = (z == 0) ? Wq : (z == 1) ? Wk : (z == 2) ? Wv : Wo;
  u16* o = out + z * WELEMS;
  const int r0 = blockIdx.y * 32, c0 = blockIdx.x * 32;
  const int tx = threadIdx.x & 31, ty = threadIdx.x >> 5;
  #pragma unroll
  for (int rr = ty; rr < 32; rr += 8)
    tile[rr][tx] = W[(r0 + rr) * D_ + c0 + tx];
  __syncthreads();
  #pragma unroll
  for (int rr = ty; rr < 32; rr += 8)
    o[(c0 + rr) * D_ + r0 + tx] = f2bf(tile[tx][rr]);
}

// ---------------- GEMM: C[M,1024] = A[M,1024] @ BT^T + bias ----------------
// MODE 0: bf16 head-split [B,H,S,64]. MODE 1: f32 row-major. MODE 2: bf16 V^T [B,H,64,S].
template <int MODE>
__device__ __forceinline__ void gemm_body(const u16* __restrict__ A,
                                          const u16* __restrict__ BT,
                                          const float* __restrict__ bias,
                                          void* __restrict__ outp,
                                          int bm, int bn) {
  __shared__ __align__(16) u16 As[128 * 32];
  __shared__ __align__(16) u16 Bs[128 * 32];
  const int tid = threadIdx.x;
  const int w = tid >> 6, l = tid & 63;
  const int wr = w >> 1, wc = w & 1;
  const int g = l >> 4, r = l & 15;

  f32x4 acc[4][4];
  #pragma unroll
  for (int i = 0; i < 4; i++)
    #pragma unroll
    for (int j = 0; j < 4; j++) acc[i][j] = (f32x4){0.f, 0.f, 0.f, 0.f};

  const int srow = l >> 2;
  const int scol = (l & 3) * 8;
  const u16* Ab = A + (bm + w * 16 + srow) * 1024 + scol;
  const u16* Bb = BT + (bn + w * 16 + srow) * 1024 + scol;
  u16* AsW = &As[(w * 16 + srow) * 32 + scol];
  u16* BsW = &Bs[(w * 16 + srow) * 32 + scol];

  for (int k0 = 0; k0 < 1024; k0 += 32) {
    async16(Ab + k0, AsW);
    async16(Ab + 64 * 1024 + k0, AsW + 64 * 32);
    async16(Bb + k0, BsW);
    async16(Bb + 64 * 1024 + k0, BsW + 64 * 32);
    __syncthreads();
    bf16x8 af[4], bf[4];
    #pragma unroll
    for (int mi = 0; mi < 4; mi++)
      af[mi] = *(const bf16x8*)&As[(wr * 64 + mi * 16 + r) * 32 + g * 8];
    #pragma unroll
    for (int ni = 0; ni < 4; ni++)
      bf[ni] = *(const bf16x8*)&Bs[(wc * 64 + ni * 16 + r) * 32 + g * 8];
    #pragma unroll
    for (int mi = 0; mi < 4; mi++)
      #pragma unroll
      for (int ni = 0; ni < 4; ni++)
        acc[mi][ni] = __builtin_amdgcn_mfma_f32_16x16x32_bf16(
            af[mi], bf[ni], acc[mi][ni], 0, 0, 0);
    __syncthreads();
  }

  const int col0 = bn + wc * 64;
  float bc[4];
  #pragma unroll
  for (int ni = 0; ni < 4; ni++) bc[ni] = bias[col0 + ni * 16 + r];

  if (MODE == 0) {
    u16* out = (u16*)outp;
    #pragma unroll
    for (int mi = 0; mi < 4; mi++) {
      const int row = bm + wr * 64 + mi * 16 + g * 4;
      #pragma unroll
      for (int ni = 0; ni < 4; ni++) {
        const int col = col0 + ni * 16 + r;
        const int h = col >> 6, dk = col & 63;
        #pragma unroll
        for (int i = 0; i < 4; i++) {
          const int rr = row + i;
          const int b = rr >> 11, s = rr & 2047;
          out[(((b << 4) | h) * 2048 + s) * 64 + dk] =
              f2bf(acc[mi][ni][i] + bc[ni]);
        }
      }
    }
  } else if (MODE == 2) {
    u16* out = (u16*)outp;
    #pragma unroll
    for (int mi = 0; mi < 4; mi++) {
      const int row = bm + wr * 64 + mi * 16 + g * 4;
      #pragma unroll
      for (int ni = 0; ni < 4; ni++) {
        const int col = col0 + ni * 16 + r;
        const int h = col >> 6, dk = col & 63;
        #pragma unroll
        for (int i = 0; i < 4; i++) {
          const int rr = row + i;
          const int b = rr >> 11, s = rr & 2047;
          // V^T: [B,H,64,S]
          out[((((b << 4) | h) * 64 + dk) * 2048) + s] =
              f2bf(acc[mi][ni][i] + bc[ni]);
        }
      }
    }
  } else {
    float* out = (float*)outp;
    #pragma unroll
    for (int mi = 0; mi < 4; mi++) {
      const int row = bm + wr * 64 + mi * 16 + g * 4;
      #pragma unroll
      for (int ni = 0; ni < 4; ni++) {
        const int col = col0 + ni * 16 + r;
        #pragma unroll
        for (int i = 0; i < 4; i++)
          out[(row + i) * 1024 + col] = acc[mi][ni][i] + bc[ni];
      }
    }
  }
}

__global__ __launch_bounds__(256) void gemm_qkv_k(
    const u16* __restrict__ X, const u16* __restrict__ WT,
    const float* __restrict__ bq, const float* __restrict__ bk,
    const float* __restrict__ bv, u16* __restrict__ QKV) {
  const int z = blockIdx.z;
  const float* bias = (z == 0) ? bq : (z == 1) ? bk : bv;
  if (z == 2)
    gemm_body<2>(X + z * XELEMS, WT + z * WELEMS, bias, QKV + z * XELEMS,
                 blockIdx.x * 128, blockIdx.y * 128);
  else
    gemm_body<0>(X + z * XELEMS, WT + z * WELEMS, bias, QKV + z * XELEMS,
                 blockIdx.x * 128, blockIdx.y * 128);
}

__global__ __launch_bounds__(256) void gemm_o_k(
    const u16* __restrict__ O, const u16* __restrict__ WOT,
    const float* __restrict__ bo, float* __restrict__ out) {
  gemm_body<1>(O, WOT, bo, out, blockIdx.x * 128, blockIdx.y * 128);
}

// ---------------- causal flash attention (v3) ----------------
// Q/K: [B*H][S][64] bf16; V^T: [B*H][64][S] bf16. O: [B][S][H*64] bf16.
// 4 waves/block, 16 q-rows/wave (QTILE=64). Block pj handles q-tiles pj and
// 31-pj (33 KV tiles each). KVBLK=64; K and V^T double-buffered via
// global_load_lds with XOR-swizzled source; counted vmcnt(4); raw s_barrier.
// Swapped QK^T (mfma(K,Q)) -> per-lane scalar softmax (q = lane&15);
// P^T -> per-wave [16q][72k] LDS tile -> bf16x8 B-frags; PV = mfma(V^T, P^T).
__global__ __launch_bounds__(256) void attn_k(
    const u16* __restrict__ Qh, const u16* __restrict__ Kh,
    const u16* __restrict__ VTh, u16* __restrict__ O) {
  __shared__ __align__(16) char ldsK[2][8192];
  __shared__ __align__(16) char ldsV[2][8192];
  __shared__ __align__(16) u16 ldsP[4][16 * 72];

  const int bh = blockIdx.y;       // b*16 + h
  const int pj = blockIdx.x;       // pair index 0..15
  const int tid = threadIdx.x;
  const int w = tid >> 6, l = tid & 63;
  const int g = l >> 4, r = l & 15;
  const int b = bh >> 4, h = bh & 15;

  const u16* Qp = Qh + bh * (S_ * 64);
  const char* Kp = (const char*)(Kh + bh * (S_ * 64));
  const char* Vp = (const char*)(VTh + bh * (64 * S_));

  // staging addresses (per lane); dest is linear (hw: base + lane*16)
  int kdst[2], ksrc[2], vfix[2];
  #pragma unroll
  for (int i = 0; i < 2; i++) {
    const int o = (w * 2 + i) * 1024 + l * 16;       // byte offset in 8KB tile
    kdst[i] = o;
    ksrc[i] = o ^ (((o >> 7) & 7) << 4);             // pre-swizzled source
    const int d = o >> 7, cb = o & 127;              // V^T row d, col byte
    vfix[i] = d * (S_ * 2) + (cb ^ ((d & 7) << 4));  // + t*128 per tile
  }
  u16* Pq = &ldsP[w][0];

  #pragma unroll
  for (int pass = 0; pass < 2; pass++) {
    const int qt = pass ? (31 - pj) : pj;
    const int q0w = qt * 64 + w * 16;
    const int nt = qt + 1;
    const int qloc = w * 16 + r;

    bf16x8 qf[2];
    #pragma unroll
    for (int dh = 0; dh < 2; dh++)
      qf[dh] = *(const bf16x8*)(Qp + (q0w + r) * 64 + dh * 32 + g * 8);
    asm volatile("s_waitcnt vmcnt(0)" ::: "memory");  // clean vm counter

    f32x4 accT[4];
    #pragma unroll
    for (int dn = 0; dn < 4; dn++) accT[dn] = (f32x4){0.f, 0.f, 0.f, 0.f};
    float mrun = -1e30f, lsum = 0.f;

    // prologue: stage tile 0 -> buf 0 (4 loads/wave)
    #pragma unroll
    for (int i = 0; i < 2; i++) {
      async16(Kp + ksrc[i], &ldsK[0][0] + kdst[i]);
      async16(Vp + vfix[i], &ldsV[0][0] + kdst[i]);
    }

    for (int t = 0; t < nt; ++t) {
      const int buf = t & 1;
      if (t + 1 < nt) {
        const char* Ks = Kp + (t + 1) * 8192;
        const char* Vs = Vp + (t + 1) * 128;
        #pragma unroll
        for (int i = 0; i < 2; i++) {
          async16(Ks + ksrc[i], &ldsK[buf ^ 1][0] + kdst[i]);
          async16(Vs + vfix[i], &ldsV[buf ^ 1][0] + kdst[i]);
        }
        asm volatile("s_waitcnt vmcnt(4)" ::: "memory");  // tile t landed
      } else {
        asm volatile("s_waitcnt vmcnt(0)" ::: "memory");
      }
      asm volatile("s_barrier" ::: "memory");

      // ---- QK^T (swapped: K rows as A, Q as B) -> S^T[k][q=r] ----
      const char* Kb = &ldsK[buf][0];
      f32x4 sc[4];
      #pragma unroll
      for (int ct = 0; ct < 4; ct++) {
        const int row = ct * 16 + r;
        const int sw = (row & 7) << 4;
        bf16x8 k0 = *(const bf16x8*)(Kb + ((row * 128 + g * 16) ^ sw));
        bf16x8 k1 = *(const bf16x8*)(Kb + ((row * 128 + 64 + g * 16) ^ sw));
        f32x4 z = (f32x4){0.f, 0.f, 0.f, 0.f};
        z = __builtin_amdgcn_mfma_f32_16x16x32_bf16(k0, qf[0], z, 0, 0, 0);
        sc[ct] = __builtin_amdgcn_mfma_f32_16x16x32_bf16(k1, qf[1], z, 0, 0, 0);
      }

      // ---- scale + causal mask (diagonal tile only) ----
      const bool diag = (t == nt - 1);
      #pragma unroll
      for (int ct = 0; ct < 4; ct++)
        #pragma unroll
        for (int i = 0; i < 4; i++) {
          float s = sc[ct][i] * 0.125f;
          if (diag && (ct * 16 + g * 4 + i > qloc)) s = -1e9f;
          sc[ct][i] = s;
        }

      // ---- online softmax: per-lane scalar state (q = r) ----
      float t0 = fmaxf(fmaxf(sc[0][0], sc[0][1]), fmaxf(sc[0][2], sc[0][3]));
      float t1 = fmaxf(fmaxf(sc[1][0], sc[1][1]), fmaxf(sc[1][2], sc[1][3]));
      float t2 = fmaxf(fmaxf(sc[2][0], sc[2][1]), fmaxf(sc[2][2], sc[2][3]));
      float t3 = fmaxf(fmaxf(sc[3][0], sc[3][1]), fmaxf(sc[3][2], sc[3][3]));
      float pmax = fmaxf(fmaxf(t0, t1), fmaxf(t2, t3));
      pmax = fmaxf(pmax, __shfl_xor(pmax, 16, 64));
      pmax = fmaxf(pmax, __shfl_xor(pmax, 32, 64));
      const float mnew = fmaxf(mrun, pmax);
      const float corr = __expf(mrun - mnew);
      mrun = mnew;
      #pragma unroll
      for (int dn = 0; dn < 4; dn++)
        #pragma unroll
        for (int i = 0; i < 4; i++) accT[dn][i] *= corr;

      float ps = 0.f;
      s16x4 pb[4];
      #pragma unroll
      for (int ct = 0; ct < 4; ct++)
        #pragma unroll
        for (int i = 0; i < 4; i++) {
          const float p = __expf(sc[ct][i] - mnew);
          ps += p;
          pb[ct][i] = (short)f2bf(p);
        }
      ps += __shfl_xor(ps, 16, 64);
      ps += __shfl_xor(ps, 32, 64);
      lsum = lsum * corr + ps;

      // ---- P^T -> per-wave LDS [16 q][72 k] (consecutive-k b64 stores) ----
      #pragma unroll
      for (int ct = 0; ct < 4; ct++)
        *(s16x4*)&Pq[r * 72 + ct * 16 + g * 4] = pb[ct];
      asm volatile("s_waitcnt lgkmcnt(0)" ::: "memory");

      // ---- PV: O^T += V^T x P^T (both plain b128 LDS reads) ----
      const char* Vb = &ldsV[buf][0];
      bf16x8 pf[2];
      #pragma unroll
      for (int kp = 0; kp < 2; kp++)
        pf[kp] = *(const bf16x8*)&Pq[r * 72 + kp * 32 + g * 8];
      __builtin_amdgcn_s_setprio(1);
      #pragma unroll
      for (int dn = 0; dn < 4; dn++) {
        const int vrow = dn * 16 + r;
        const int vsw = (vrow & 7) << 4;
        #pragma unroll
        for (int kp = 0; kp < 2; kp++) {
          bf16x8 vf = *(const bf16x8*)(Vb + ((vrow * 128 + kp * 64 + g * 16) ^ vsw));
          accT[dn] = __builtin_amdgcn_mfma_f32_16x16x32_bf16(vf, pf[kp], accT[dn], 0, 0, 0);
        }
      }
      __builtin_amdgcn_s_setprio(0);
      asm volatile("s_barrier" ::: "memory");
    }

    // ---- epilogue: O[b][q][h*64+d] = accT^T / lsum ----
    const float inv = 1.0f / lsum;
    const int qrow = q0w + r;
    #pragma unroll
    for (int dn = 0; dn < 4; dn++) {
      u16 o0 = f2bf(accT[dn][0] * inv), o1 = f2bf(accT[dn][1] * inv);
      u16 o2 = f2bf(accT[dn][2] * inv), o3 = f2bf(accT[dn][3] * inv);
      uint2 pk;
      pk.x = (unsigned)o0 | ((unsigned)o1 << 16);
      pk.y = (unsigned)o2 | ((unsigned)o3 << 16);
      *(uint2*)(O + ((size_t)(b * 2048 + qrow)) * 1024 + h * 64 + dn * 16 + g * 4) = pk;
    }
  }
}

// ---------------- launcher ----------------
extern "C" void kernel_launch(void* const* d_in, const int* in_sizes, int n_in,
                              void* d_out, int out_size, void* d_ws, size_t ws_size,
                              hipStream_t stream) {
  const float* q  = (const float*)d_in[0];
  const float* k  = (const float*)d_in[1];
  const float* v  = (const float*)d_in[2];
  // d_in[3] = mask (causal triu) — applied analytically
  const float* Wq = (const float*)d_in[4];
  const float* bq = (const float*)d_in[5];
  const float* Wk = (const float*)d_in[6];
  const float* bk = (const float*)d_in[7];
  const float* Wv = (const float*)d_in[8];
  const float* bv = (const float*)d_in[9];
  const float* Wo = (const float*)d_in[10];
  const float* bo = (const float*)d_in[11];

  char* ws = (char*)d_ws;
  const size_t MB = 1u << 20;
  u16* X   = (u16*)(ws);             // 3 x XELEMS bf16 (24MB)
  u16* WT  = (u16*)(ws + 24 * MB);   // 4 x WELEMS bf16 (8MB)
  u16* QKV = (u16*)(ws + 32 * MB);   // Q,K: [B,H,S,64]; V^T: [B,H,64,S] (24MB)
  u16* O   = (u16*)(ws);             // reuse X region after projections

  hipLaunchKernelGGL(convert_x, dim3(1024), dim3(256), 0, stream, q, k, v, X);
  hipLaunchKernelGGL(transpose_w, dim3(32, 32, 4), dim3(256), 0, stream,
                     Wq, Wk, Wv, Wo, WT);
  hipLaunchKernelGGL(gemm_qkv_k, dim3(32, 8, 3), dim3(256), 0, stream,
                     X, WT, bq, bk, bv, QKV);
  hipLaunchKernelGGL(attn_k, dim3(16, 32), dim3(256), 0, stream,
                     QKV, QKV + XELEMS, QKV + 2 * XELEMS, O);
  hipLaunchKernelGGL(gemm_o_k, dim3(32, 8), dim3(256), 0, stream,
                     O, WT + 3 * WELEMS, bo, (float*)d_out);
}

// Round 4
// 137.298 us; speedup vs baseline: 1.9920x; 1.0755x over previous
//
#include <hip/hip_runtime.h>
#include <hip/hip_bf16.h>
#include <stdint.h>

typedef unsigned short u16;
typedef __attribute__((ext_vector_type(4))) float f32x4;
typedef __attribute__((ext_vector_type(8))) short bf16x8;
typedef __attribute__((ext_vector_type(4))) short s16x4;

#define B_ 2
#define S_ 2048
#define H_ 16
#define D_ 1024
#define XELEMS (B_*S_*D_)      // 4194304 per tensor
#define WELEMS (D_*D_)         // 1048576 per weight

__device__ __forceinline__ u16 f2bf(float f) {
  union { float f; unsigned u; } v; v.f = f;
  unsigned r = v.u + 0x7fffu + ((v.u >> 16) & 1u);
  return (u16)(r >> 16);
}

__device__ __forceinline__ void async16(const void* g, void* l) {
  __builtin_amdgcn_global_load_lds(
      (const __attribute__((address_space(1))) unsigned int*)g,
      (__attribute__((address_space(3))) unsigned int*)l, 16, 0, 0);
}

#if __has_builtin(__builtin_amdgcn_exp2f)
#define EXP2(x) __builtin_amdgcn_exp2f(x)
#else
#define EXP2(x) exp2f(x)
#endif

__device__ __forceinline__ unsigned cvtpk(float a, float b) {
  unsigned r;
  asm("v_cvt_pk_bf16_f32 %0, %1, %2" : "=v"(r) : "v"(a), "v"(b));
  return r;
}

// ---------------- prep: W transpose (blocks 0..4095) + X convert (4096..5119) ----
__global__ __launch_bounds__(256) void prep_k(
    const float* __restrict__ q, const float* __restrict__ k,
    const float* __restrict__ v,
    const float* __restrict__ Wq, const float* __restrict__ Wk,
    const float* __restrict__ Wv, const float* __restrict__ Wo,
    u16* __restrict__ X, u16* __restrict__ WT) {
  const int bid = blockIdx.x;
  if (bid < 4096) {
    __shared__ float tile[32][33];
    const int z = bid >> 10, rem = bid & 1023;
    const float* W = (z == 0) ? Wq : (z == 1) ? Wk : (z == 2) ? Wv : Wo;
    u16* o = WT + z * WELEMS;
    const int r0 = (rem >> 5) << 5, c0 = (rem & 31) << 5;
    const int tx = threadIdx.x & 31, ty = threadIdx.x >> 5;
    #pragma unroll
    for (int rr = ty; rr < 32; rr += 8)
      tile[rr][tx] = W[(r0 + rr) * D_ + c0 + tx];
    __syncthreads();
    #pragma unroll
    for (int rr = ty; rr < 32; rr += 8)
      o[(c0 + rr) * D_ + r0 + tx] = f2bf(tile[tx][rr]);
  } else {
    const int cb = bid - 4096;                 // 0..1023
    const int ngrp = XELEMS / 8;
    const int total = 3 * ngrp;
    for (int i = cb * 256 + threadIdx.x; i < total; i += 1024 * 256) {
      int which = i / ngrp;
      int off = (i - which * ngrp) * 8;
      const float* src = (which == 0) ? q : (which == 1) ? k : v;
      float4 a = *(const float4*)(src + off);
      float4 b = *(const float4*)(src + off + 4);
      u16 rr[8] = {f2bf(a.x), f2bf(a.y), f2bf(a.z), f2bf(a.w),
                   f2bf(b.x), f2bf(b.y), f2bf(b.z), f2bf(b.w)};
      uint4 pk;
      pk.x = (unsigned)rr[0] | ((unsigned)rr[1] << 16);
      pk.y = (unsigned)rr[2] | ((unsigned)rr[3] << 16);
      pk.z = (unsigned)rr[4] | ((unsigned)rr[5] << 16);
      pk.w = (unsigned)rr[6] | ((unsigned)rr[7] << 16);
      *(uint4*)(X + which * XELEMS + off) = pk;
    }
  }
}

// ---------------- GEMM: C[M,1024] = A[M,1024] @ BT^T + bias (BK=64, swizzled) ---
// MODE 0: bf16 head-split [B,H,S,64]. MODE 1: f32 row-major. MODE 2: bf16 V^T [B,H,64,S].
template <int MODE>
__device__ __forceinline__ void gemm_body(const u16* __restrict__ A,
                                          const u16* __restrict__ BT,
                                          const float* __restrict__ bias,
                                          void* __restrict__ outp,
                                          int bm, int bn) {
  __shared__ __align__(16) u16 As[128 * 64];
  __shared__ __align__(16) u16 Bs[128 * 64];
  const int tid = threadIdx.x;
  const int w = tid >> 6, l = tid & 63;
  const int wr = w >> 1, wc = w & 1;
  const int g = l >> 4, r = l & 15;
  (void)w; (void)l;

  f32x4 acc[4][4];
  #pragma unroll
  for (int i = 0; i < 4; i++)
    #pragma unroll
    for (int j = 0; j < 4; j++) acc[i][j] = (f32x4){0.f, 0.f, 0.f, 0.f};

  // staging: swizzled image in LDS, linear dest + pre-swizzled source
  int dst[4], aoff[4], boff[4];
  #pragma unroll
  for (int i = 0; i < 4; i++) {
    const int o = i * 4096 + tid * 16;         // byte offset in 16KB tile
    dst[i] = o;
    const int row = o >> 7;                    // 0..127
    const int cbyte = (o & 127) ^ ((row & 7) << 4);
    aoff[i] = (bm + row) * 1024 + (cbyte >> 1);
    boff[i] = (bn + row) * 1024 + (cbyte >> 1);
  }

  for (int k0 = 0; k0 < 1024; k0 += 64) {
    #pragma unroll
    for (int i = 0; i < 4; i++) async16(A + aoff[i] + k0, (char*)As + dst[i]);
    #pragma unroll
    for (int i = 0; i < 4; i++) async16(BT + boff[i] + k0, (char*)Bs + dst[i]);
    __syncthreads();
    bf16x8 af[2][4], bf[2][4];
    #pragma unroll
    for (int kk = 0; kk < 2; kk++)
      #pragma unroll
      for (int mi = 0; mi < 4; mi++) {
        const int rA = wr * 64 + mi * 16 + r;
        af[kk][mi] = *(const bf16x8*)((const char*)As +
            ((rA * 128 + kk * 64 + g * 16) ^ ((rA & 7) << 4)));
      }
    #pragma unroll
    for (int kk = 0; kk < 2; kk++)
      #pragma unroll
      for (int ni = 0; ni < 4; ni++) {
        const int rB = wc * 64 + ni * 16 + r;
        bf[kk][ni] = *(const bf16x8*)((const char*)Bs +
            ((rB * 128 + kk * 64 + g * 16) ^ ((rB & 7) << 4)));
      }
    #pragma unroll
    for (int kk = 0; kk < 2; kk++)
      #pragma unroll
      for (int mi = 0; mi < 4; mi++)
        #pragma unroll
        for (int ni = 0; ni < 4; ni++)
          acc[mi][ni] = __builtin_amdgcn_mfma_f32_16x16x32_bf16(
              af[kk][mi], bf[kk][ni], acc[mi][ni], 0, 0, 0);
    __syncthreads();
  }

  const int col0 = bn + wc * 64;
  float bc[4];
  #pragma unroll
  for (int ni = 0; ni < 4; ni++) bc[ni] = bias[col0 + ni * 16 + r];

  if (MODE == 0) {
    u16* out = (u16*)outp;
    #pragma unroll
    for (int mi = 0; mi < 4; mi++) {
      const int row = bm + wr * 64 + mi * 16 + g * 4;
      #pragma unroll
      for (int ni = 0; ni < 4; ni++) {
        const int col = col0 + ni * 16 + r;
        const int h = col >> 6, dk = col & 63;
        #pragma unroll
        for (int i = 0; i < 4; i++) {
          const int rr = row + i;
          const int b = rr >> 11, s = rr & 2047;
          out[(((b << 4) | h) * 2048 + s) * 64 + dk] =
              f2bf(acc[mi][ni][i] + bc[ni]);
        }
      }
    }
  } else if (MODE == 2) {
    u16* out = (u16*)outp;
    #pragma unroll
    for (int mi = 0; mi < 4; mi++) {
      const int row = bm + wr * 64 + mi * 16 + g * 4;
      #pragma unroll
      for (int ni = 0; ni < 4; ni++) {
        const int col = col0 + ni * 16 + r;
        const int h = col >> 6, dk = col & 63;
        #pragma unroll
        for (int i = 0; i < 4; i++) {
          const int rr = row + i;
          const int b = rr >> 11, s = rr & 2047;
          out[((((b << 4) | h) * 64 + dk) * 2048) + s] =
              f2bf(acc[mi][ni][i] + bc[ni]);
        }
      }
    }
  } else {
    float* out = (float*)outp;
    #pragma unroll
    for (int mi = 0; mi < 4; mi++) {
      const int row = bm + wr * 64 + mi * 16 + g * 4;
      #pragma unroll
      for (int ni = 0; ni < 4; ni++) {
        const int col = col0 + ni * 16 + r;
        #pragma unroll
        for (int i = 0; i < 4; i++)
          out[(row + i) * 1024 + col] = acc[mi][ni][i] + bc[ni];
      }
    }
  }
}

__global__ __launch_bounds__(256) void gemm_qkv_k(
    const u16* __restrict__ X, const u16* __restrict__ WT,
    const float* __restrict__ bq, const float* __restrict__ bk,
    const float* __restrict__ bv, u16* __restrict__ QKV) {
  const int z = blockIdx.z;
  const float* bias = (z == 0) ? bq : (z == 1) ? bk : bv;
  if (z == 2)
    gemm_body<2>(X + z * XELEMS, WT + z * WELEMS, bias, QKV + z * XELEMS,
                 blockIdx.x * 128, blockIdx.y * 128);
  else
    gemm_body<0>(X + z * XELEMS, WT + z * WELEMS, bias, QKV + z * XELEMS,
                 blockIdx.x * 128, blockIdx.y * 128);
}

__global__ __launch_bounds__(256) void gemm_o_k(
    const u16* __restrict__ O, const u16* __restrict__ WOT,
    const float* __restrict__ bo, float* __restrict__ out) {
  gemm_body<1>(O, WOT, bo, out, blockIdx.x * 128, blockIdx.y * 128);
}

// ---------------- causal flash attention (v4) ----------------
// Q/K: [B*H][S][64] bf16; V^T: [B*H][64][S] bf16. O: [B][S][H*64] bf16.
// Same pipeline as v3 (passed): 4 waves, QTILE=64/block-pass, pairing pj/31-pj,
// KVBLK=64 double-buffered gload_lds + counted vmcnt(4) + raw s_barrier.
// v4 softmax diet: base-2 exp, max3 tree, defer-max (THR=11 in log2 units),
// v_cvt_pk_bf16_f32 P-packing.
__global__ __launch_bounds__(256) void attn_k(
    const u16* __restrict__ Qh, const u16* __restrict__ Kh,
    const u16* __restrict__ VTh, u16* __restrict__ O) {
  __shared__ __align__(16) char ldsK[2][8192];
  __shared__ __align__(16) char ldsV[2][8192];
  __shared__ __align__(16) u16 ldsP[4][16 * 72];

  const int bh = blockIdx.y;       // b*16 + h
  const int pj = blockIdx.x;       // pair index 0..15
  const int tid = threadIdx.x;
  const int w = tid >> 6, l = tid & 63;
  const int g = l >> 4, r = l & 15;
  const int b = bh >> 4, h = bh & 15;

  const u16* Qp = Qh + bh * (S_ * 64);
  const char* Kp = (const char*)(Kh + bh * (S_ * 64));
  const char* Vp = (const char*)(VTh + bh * (64 * S_));

  int kdst[2], ksrc[2], vfix[2];
  #pragma unroll
  for (int i = 0; i < 2; i++) {
    const int o = (w * 2 + i) * 1024 + l * 16;       // byte offset in 8KB tile
    kdst[i] = o;
    ksrc[i] = o ^ (((o >> 7) & 7) << 4);
    const int d = o >> 7, cbyte = o & 127;           // V^T row d, col byte
    vfix[i] = d * (S_ * 2) + (cbyte ^ ((d & 7) << 4));
  }
  u16* Pq = &ldsP[w][0];

  #pragma unroll
  for (int pass = 0; pass < 2; pass++) {
    const int qt = pass ? (31 - pj) : pj;
    const int q0w = qt * 64 + w * 16;
    const int nt = qt + 1;
    const int qloc = w * 16 + r;

    bf16x8 qf[2];
    #pragma unroll
    for (int dh = 0; dh < 2; dh++)
      qf[dh] = *(const bf16x8*)(Qp + (q0w + r) * 64 + dh * 32 + g * 8);
    asm volatile("s_waitcnt vmcnt(0)" ::: "memory");  // clean vm counter

    f32x4 accT[4];
    #pragma unroll
    for (int dn = 0; dn < 4; dn++) accT[dn] = (f32x4){0.f, 0.f, 0.f, 0.f};
    float mrun = -1e30f, lsum = 0.f;

    #pragma unroll
    for (int i = 0; i < 2; i++) {
      async16(Kp + ksrc[i], &ldsK[0][0] + kdst[i]);
      async16(Vp + vfix[i], &ldsV[0][0] + kdst[i]);
    }

    for (int t = 0; t < nt; ++t) {
      const int buf = t & 1;
      if (t + 1 < nt) {
        const char* Ks = Kp + (t + 1) * 8192;
        const char* Vs = Vp + (t + 1) * 128;
        #pragma unroll
        for (int i = 0; i < 2; i++) {
          async16(Ks + ksrc[i], &ldsK[buf ^ 1][0] + kdst[i]);
          async16(Vs + vfix[i], &ldsV[buf ^ 1][0] + kdst[i]);
        }
        asm volatile("s_waitcnt vmcnt(4)" ::: "memory");
      } else {
        asm volatile("s_waitcnt vmcnt(0)" ::: "memory");
      }
      asm volatile("s_barrier" ::: "memory");

      // ---- QK^T (swapped) -> S^T[k][q=r], in log2 units ----
      const char* Kb = &ldsK[buf][0];
      f32x4 sc[4];
      #pragma unroll
      for (int ct = 0; ct < 4; ct++) {
        const int row = ct * 16 + r;
        const int sw = (row & 7) << 4;
        bf16x8 k0 = *(const bf16x8*)(Kb + ((row * 128 + g * 16) ^ sw));
        bf16x8 k1 = *(const bf16x8*)(Kb + ((row * 128 + 64 + g * 16) ^ sw));
        f32x4 z = (f32x4){0.f, 0.f, 0.f, 0.f};
        z = __builtin_amdgcn_mfma_f32_16x16x32_bf16(k0, qf[0], z, 0, 0, 0);
        sc[ct] = __builtin_amdgcn_mfma_f32_16x16x32_bf16(k1, qf[1], z, 0, 0, 0);
      }

      const bool diag = (t == nt - 1);
      #pragma unroll
      for (int ct = 0; ct < 4; ct++)
        #pragma unroll
        for (int i = 0; i < 4; i++) {
          float s = sc[ct][i] * 0.18033688f;   // (1/8) * log2(e)
          if (diag && (ct * 16 + g * 4 + i > qloc)) s = -1e9f;
          sc[ct][i] = s;
        }

      // ---- max via v_max3 tree + 2 shuffles ----
      float a0 = fmaxf(fmaxf(sc[0][0], sc[0][1]), sc[0][2]);
      float a1 = fmaxf(fmaxf(sc[0][3], sc[1][0]), sc[1][1]);
      float a2 = fmaxf(fmaxf(sc[1][2], sc[1][3]), sc[2][0]);
      float a3 = fmaxf(fmaxf(sc[2][1], sc[2][2]), sc[2][3]);
      float a4 = fmaxf(fmaxf(sc[3][0], sc[3][1]), sc[3][2]);
      float pmax = fmaxf(fmaxf(fmaxf(a0, a1), fmaxf(a2, a3)),
                         fmaxf(a4, sc[3][3]));
      pmax = fmaxf(pmax, __shfl_xor(pmax, 16, 64));
      pmax = fmaxf(pmax, __shfl_xor(pmax, 32, 64));

      // ---- defer-max rescale (THR = 11 in log2 units; p <= 2^11) ----
      if (!__all(pmax - mrun <= 11.0f)) {
        const float mnew = fmaxf(mrun, pmax);
        const float corr = EXP2(mrun - mnew);
        mrun = mnew;
        #pragma unroll
        for (int dn = 0; dn < 4; dn++)
          #pragma unroll
          for (int i = 0; i < 4; i++) accT[dn][i] *= corr;
        lsum *= corr;
      }

      float ps = 0.f;
      #pragma unroll
      for (int ct = 0; ct < 4; ct++)
        #pragma unroll
        for (int i = 0; i < 4; i++) {
          const float p = EXP2(sc[ct][i] - mrun);
          sc[ct][i] = p;
          ps += p;
        }
      ps += __shfl_xor(ps, 16, 64);
      ps += __shfl_xor(ps, 32, 64);
      lsum += ps;

      // ---- pack P via v_cvt_pk_bf16_f32, store to per-wave LDS ----
      #pragma unroll
      for (int ct = 0; ct < 4; ct++) {
        uint2 pk;
        pk.x = cvtpk(sc[ct][0], sc[ct][1]);
        pk.y = cvtpk(sc[ct][2], sc[ct][3]);
        *(uint2*)&Pq[r * 72 + ct * 16 + g * 4] = pk;
      }
      asm volatile("s_waitcnt lgkmcnt(0)" ::: "memory");

      // ---- PV: O^T += V^T x P^T ----
      const char* Vb = &ldsV[buf][0];
      bf16x8 pf[2];
      #pragma unroll
      for (int kp = 0; kp < 2; kp++)
        pf[kp] = *(const bf16x8*)&Pq[r * 72 + kp * 32 + g * 8];
      __builtin_amdgcn_s_setprio(1);
      #pragma unroll
      for (int dn = 0; dn < 4; dn++) {
        const int vrow = dn * 16 + r;
        const int vsw = (vrow & 7) << 4;
        #pragma unroll
        for (int kp = 0; kp < 2; kp++) {
          bf16x8 vf = *(const bf16x8*)(Vb + ((vrow * 128 + kp * 64 + g * 16) ^ vsw));
          accT[dn] = __builtin_amdgcn_mfma_f32_16x16x32_bf16(vf, pf[kp], accT[dn], 0, 0, 0);
        }
      }
      __builtin_amdgcn_s_setprio(0);
      asm volatile("s_barrier" ::: "memory");
    }

    // ---- epilogue ----
    const float inv = 1.0f / lsum;
    const int qrow = q0w + r;
    #pragma unroll
    for (int dn = 0; dn < 4; dn++) {
      u16 o0 = f2bf(accT[dn][0] * inv), o1 = f2bf(accT[dn][1] * inv);
      u16 o2 = f2bf(accT[dn][2] * inv), o3 = f2bf(accT[dn][3] * inv);
      uint2 pk;
      pk.x = (unsigned)o0 | ((unsigned)o1 << 16);
      pk.y = (unsigned)o2 | ((unsigned)o3 << 16);
      *(uint2*)(O + ((size_t)(b * 2048 + qrow)) * 1024 + h * 64 + dn * 16 + g * 4) = pk;
    }
  }
}

// ---------------- launcher ----------------
extern "C" void kernel_launch(void* const* d_in, const int* in_sizes, int n_in,
                              void* d_out, int out_size, void* d_ws, size_t ws_size,
                              hipStream_t stream) {
  const float* q  = (const float*)d_in[0];
  const float* k  = (const float*)d_in[1];
  const float* v  = (const float*)d_in[2];
  // d_in[3] = mask (causal triu) — applied analytically
  const float* Wq = (const float*)d_in[4];
  const float* bq = (const float*)d_in[5];
  const float* Wk = (const float*)d_in[6];
  const float* bk = (const float*)d_in[7];
  const float* Wv = (const float*)d_in[8];
  const float* bv = (const float*)d_in[9];
  const float* Wo = (const float*)d_in[10];
  const float* bo = (const float*)d_in[11];

  char* ws = (char*)d_ws;
  const size_t MB = 1u << 20;
  u16* X   = (u16*)(ws);             // 3 x XELEMS bf16 (24MB)
  u16* WT  = (u16*)(ws + 24 * MB);   // 4 x WELEMS bf16 (8MB)
  u16* QKV = (u16*)(ws + 32 * MB);   // Q,K: [B,H,S,64]; V^T: [B,H,64,S] (24MB)
  u16* O   = (u16*)(ws);             // reuse X region after projections

  hipLaunchKernelGGL(prep_k, dim3(5120), dim3(256), 0, stream,
                     q, k, v, Wq, Wk, Wv, Wo, X, WT);
  hipLaunchKernelGGL(gemm_qkv_k, dim3(32, 8, 3), dim3(256), 0, stream,
                     X, WT, bq, bk, bv, QKV);
  hipLaunchKernelGGL(attn_k, dim3(16, 32), dim3(256), 0, stream,
                     QKV, QKV + XELEMS, QKV + 2 * XELEMS, O);
  hipLaunchKernelGGL(gemm_o_k, dim3(32, 8), dim3(256), 0, stream,
                     O, WT + 3 * WELEMS, bo, (float*)d_out);
}